// Round 1
// baseline (1249.629 us; speedup 1.0000x reference)
//
#include <hip/hip_runtime.h>
#include <math.h>

#define NPTS 8192
#define NB 2
#define FDIM 96
#define KNN 20
#define OC 64
#define VN_EPS 1e-6f
#define VN_BN_EPS 1e-5f

// ---------------- Kernel 1: xx[b*N+m] = sum_f xf^2 ----------------
__global__ __launch_bounds__(256) void k_xx(const float* __restrict__ x,
                                            float* __restrict__ xx) {
    int m = blockIdx.x * 256 + threadIdx.x;       // global point b*N+n
    int b = m >> 13, n = m & 8191;
    const float* xf = x + (size_t)b * FDIM * NPTS;
    float s = 0.f;
    #pragma unroll
    for (int f = 0; f < FDIM; ++f) {
        float v = xf[(size_t)f * NPTS + n];
        s += v * v;
    }
    xx[m] = s;
}

// ---------------- Kernel 2: neg-dist tile GEMM ----------------
// dbuf[localRow][m] = 2*dot(n,m) - xx[n] - xx[m]
__global__ __launch_bounds__(256) void k_dist(const float* __restrict__ x,
                                              const float* __restrict__ xx,
                                              float* __restrict__ dbuf,
                                              int rowStart) {
    __shared__ __align__(16) float As[FDIM][64];
    __shared__ __align__(16) float Bs[FDIM][64];
    int row0 = rowStart + blockIdx.x * 64;        // global row b*N+n
    int b = row0 >> 13, n0 = row0 & 8191;
    int m0 = blockIdx.y * 64;
    const float* xf = x + (size_t)b * FDIM * NPTS;
    int t = threadIdx.x;
    for (int i = t; i < FDIM * 64; i += 256) {
        int f = i >> 6, c = i & 63;
        As[f][c] = xf[(size_t)f * NPTS + n0 + c];
        Bs[f][c] = xf[(size_t)f * NPTS + m0 + c];
    }
    __syncthreads();
    int tx = t & 15, ty = t >> 4;
    float acc[4][4] = {};
    for (int kf = 0; kf < FDIM; ++kf) {
        float4 av = *(const float4*)&As[kf][ty * 4];
        float4 bv = *(const float4*)&Bs[kf][tx * 4];
        float aa[4] = {av.x, av.y, av.z, av.w};
        float bb[4] = {bv.x, bv.y, bv.z, bv.w};
        #pragma unroll
        for (int i = 0; i < 4; ++i)
            #pragma unroll
            for (int j = 0; j < 4; ++j)
                acc[i][j] += aa[i] * bb[j];
    }
    int lrow0 = row0 - rowStart;
    float xc0 = xx[(b << 13) + m0 + tx * 4 + 0];
    float xc1 = xx[(b << 13) + m0 + tx * 4 + 1];
    float xc2 = xx[(b << 13) + m0 + tx * 4 + 2];
    float xc3 = xx[(b << 13) + m0 + tx * 4 + 3];
    #pragma unroll
    for (int i = 0; i < 4; ++i) {
        int rr = ty * 4 + i;
        float xr = xx[row0 + rr];
        float4 o4;
        o4.x = 2.f * acc[i][0] - xr - xc0;
        o4.y = 2.f * acc[i][1] - xr - xc1;
        o4.z = 2.f * acc[i][2] - xr - xc2;
        o4.w = 2.f * acc[i][3] - xr - xc3;
        *(float4*)&dbuf[(size_t)(lrow0 + rr) * NPTS + m0 + tx * 4] = o4;
    }
}

// ---------------- Kernel 3: top-20 per row (iterative extraction) ----------------
__global__ __launch_bounds__(256) void k_topk(const float* __restrict__ dbuf,
                                              int* __restrict__ idxOut,
                                              int rowStart) {
    int r = blockIdx.x;
    const float* row = dbuf + (size_t)r * NPTS;
    int t = threadIdx.x;
    float vals[32];
    #pragma unroll
    for (int i = 0; i < 32; ++i) vals[i] = row[t + (i << 8)];
    unsigned taken = 0u;
    float bv = -3.4e38f;
    int bi = 0x7fffffff;
    for (int i = 0; i < 32; ++i) {
        float vv = vals[i];
        if (vv > bv) { bv = vv; bi = t + (i << 8); }
    }
    __shared__ float swv[4];
    __shared__ int swi[4];
    __shared__ int sbi;
    int grow = rowStart + r;
    for (int kk = 0; kk < KNN; ++kk) {
        float rv = bv;
        int ri = bi;
        #pragma unroll
        for (int off = 1; off < 64; off <<= 1) {
            float ov = __shfl_xor(rv, off);
            int oi = __shfl_xor(ri, off);
            if (ov > rv || (ov == rv && oi < ri)) { rv = ov; ri = oi; }
        }
        if ((t & 63) == 0) { swv[t >> 6] = rv; swi[t >> 6] = ri; }
        __syncthreads();
        if (t == 0) {
            float fv = swv[0]; int fi = swi[0];
            #pragma unroll
            for (int w = 1; w < 4; ++w) {
                if (swv[w] > fv || (swv[w] == fv && swi[w] < fi)) { fv = swv[w]; fi = swi[w]; }
            }
            idxOut[(size_t)grow * KNN + kk] = fi;
            sbi = fi;
        }
        __syncthreads();
        int win = sbi;
        __syncthreads();
        if ((win & 255) == t) {
            taken |= 1u << (win >> 8);
            bv = -3.4e38f; bi = 0x7fffffff;
            for (int i = 0; i < 32; ++i) {
                if ((taken >> i) & 1u) continue;
                float vv = vals[i];
                if (vv > bv) { bv = vv; bi = t + (i << 8); }
            }
        }
    }
}

// ---------------- Kernel 4: u = A*x_point, v = (B-A)*x_point ----------------
// u,v layout: [(b*N+pt)*64 + o]*3 + d   (contiguous 192 floats per point)
__global__ __launch_bounds__(256) void k_uv(const float* __restrict__ x,
                                            const float* __restrict__ W1,
                                            float* __restrict__ u,
                                            float* __restrict__ v) {
    __shared__ float sA[64 * 33];
    __shared__ float sV[64 * 33];
    __shared__ float sxf[FDIM * 16];
    int t = threadIdx.x;
    for (int i = t; i < 64 * 32; i += 256) {
        int o = i >> 5, c = i & 31;
        float a = W1[o * 64 + c];
        sA[o * 33 + c] = a;
        sV[o * 33 + c] = W1[o * 64 + 32 + c] - a;
    }
    int p0 = blockIdx.x * 16;
    int b = p0 >> 13, nb = p0 & 8191;
    const float* xf = x + (size_t)b * FDIM * NPTS;
    for (int i = t; i < FDIM * 16; i += 256) {
        int f = i >> 4, p = i & 15;
        sxf[f * 16 + p] = xf[(size_t)f * NPTS + nb + p];
    }
    __syncthreads();
    #pragma unroll
    for (int ii = 0; ii < 4; ++ii) {
        int it = t + 256 * ii;
        int o = it & 63, p = it >> 6;
        float u0 = 0.f, u1 = 0.f, u2 = 0.f, w0 = 0.f, w1 = 0.f, w2 = 0.f;
        #pragma unroll
        for (int c = 0; c < 32; ++c) {
            float a = sA[o * 33 + c];
            float wv = sV[o * 33 + c];
            float x0 = sxf[(c * 3 + 0) * 16 + p];
            float x1 = sxf[(c * 3 + 1) * 16 + p];
            float x2 = sxf[(c * 3 + 2) * 16 + p];
            u0 += a * x0;  u1 += a * x1;  u2 += a * x2;
            w0 += wv * x0; w1 += wv * x1; w2 += wv * x2;
        }
        size_t base = ((size_t)(p0 + p) * 64 + o) * 3;
        u[base] = u0; u[base + 1] = u1; u[base + 2] = u2;
        v[base] = w0; v[base + 1] = w1; v[base + 2] = w2;
    }
}

// ---------------- Kernel 5: BN stats partials (8 points/block) ----------------
__global__ __launch_bounds__(256) void k_stats(const float* __restrict__ u,
                                               const float* __restrict__ v,
                                               const int* __restrict__ idx,
                                               float* __restrict__ partial) {
    int blk = blockIdx.x, t = threadIdx.x;
    int o = t & 63, sub = t >> 6;
    int p0 = blk * 8;
    __shared__ float svf[8 * 192];
    __shared__ int sjf[8 * KNN];
    for (int i = t; i < 8 * 192; i += 256) svf[i] = v[(size_t)p0 * 192 + i];
    for (int i = t; i < 8 * KNN; i += 256) sjf[i] = idx[(size_t)p0 * KNN + i];
    __syncthreads();
    float s1 = 0.f, s2 = 0.f;
    for (int p = 0; p < 8; ++p) {
        int gpt = p0 + p;
        size_t ubase = (size_t)(gpt >> 13) * NPTS * 192;
        const float* vp = &svf[p * 192 + o * 3];
        float v0 = vp[0], v1 = vp[1], v2 = vp[2];
        for (int kk = sub; kk < KNN; kk += 4) {
            int j = sjf[p * KNN + kk];
            const float* up = u + ubase + (size_t)j * 192 + o * 3;
            float q0 = up[0] + v0, q1 = up[1] + v1, q2 = up[2] + v2;
            float nrm = sqrtf(q0 * q0 + q1 * q1 + q2 * q2) + VN_EPS;
            s1 += nrm;
            s2 += nrm * nrm;
        }
    }
    __shared__ float r1[256], r2[256];
    r1[t] = s1; r2[t] = s2;
    __syncthreads();
    if (t < 64) {
        float a1 = r1[t] + r1[t + 64] + r1[t + 128] + r1[t + 192];
        float a2 = r2[t] + r2[t + 64] + r2[t + 128] + r2[t + 192];
        partial[(size_t)blk * 128 + t] = a1;
        partial[(size_t)blk * 128 + 64 + t] = a2;
    }
}

// ---------------- Kernel 6: reduce stats -> gs, bs ----------------
__global__ __launch_bounds__(256) void k_reduce(const float* __restrict__ partial,
                                                const float* __restrict__ gamma,
                                                const float* __restrict__ beta,
                                                float* __restrict__ gsbs) {
    int ch = blockIdx.x, t = threadIdx.x;
    float s1 = 0.f, s2 = 0.f;
    for (int i = t; i < 2048; i += 256) {
        s1 += partial[(size_t)i * 128 + ch];
        s2 += partial[(size_t)i * 128 + 64 + ch];
    }
    __shared__ float r1[256], r2[256];
    r1[t] = s1; r2[t] = s2;
    __syncthreads();
    for (int s = 128; s > 0; s >>= 1) {
        if (t < s) { r1[t] += r1[t + s]; r2[t] += r2[t + s]; }
        __syncthreads();
    }
    if (t == 0) {
        const float cnt = (float)(NB * NPTS * KNN);
        float mean = r1[0] / cnt;
        float var = r2[0] / cnt - mean * mean;
        float inv = 1.0f / sqrtf(var + VN_BN_EPS);
        float g = gamma[ch] * inv;
        gsbs[ch] = g;
        gsbs[64 + ch] = beta[ch] - mean * g;
    }
}

// ---------------- Kernel 7: fused BN + VN-LeakyReLU + mean over k ----------------
__global__ __launch_bounds__(256) void k_final(const float* __restrict__ u,
                                               const float* __restrict__ v,
                                               const int* __restrict__ idx,
                                               const float* __restrict__ Wd,
                                               const float* __restrict__ gsbs,
                                               float* __restrict__ out) {
    int t = threadIdx.x;
    int o = t & 63, grp = t >> 6;
    int gpt = blockIdx.x * 4 + grp;              // global point b*N+n
    int b = gpt >> 13, n = gpt & 8191;
    float wd[64];
    #pragma unroll
    for (int c = 0; c < 64; ++c) wd[c] = Wd[o * 64 + c];
    float gso = gsbs[o], bso = gsbs[64 + o];
    __shared__ __align__(16) float spb[4][3 * 64];
    size_t vb = (size_t)gpt * 192 + o * 3;
    float v0 = v[vb], v1 = v[vb + 1], v2 = v[vb + 2];
    const int* jrow = idx + (size_t)gpt * KNN;
    size_t ubase = (size_t)b * NPTS * 192;
    float a0 = 0.f, a1 = 0.f, a2 = 0.f;
    for (int kk = 0; kk < KNN; ++kk) {
        int j = jrow[kk];
        const float* up = u + ubase + (size_t)j * 192 + o * 3;
        float q0 = up[0] + v0, q1 = up[1] + v1, q2 = up[2] + v2;
        float nrm = sqrtf(q0 * q0 + q1 * q1 + q2 * q2) + VN_EPS;
        float f = (gso * nrm + bso) / nrm;
        q0 *= f; q1 *= f; q2 *= f;
        spb[grp][o] = q0;
        spb[grp][64 + o] = q1;
        spb[grp][128 + o] = q2;
        __syncthreads();
        float d0 = 0.f, d1 = 0.f, d2 = 0.f;
        #pragma unroll
        for (int c = 0; c < 64; c += 4) {
            float4 x0 = *(const float4*)&spb[grp][c];
            float4 x1 = *(const float4*)&spb[grp][64 + c];
            float4 x2 = *(const float4*)&spb[grp][128 + c];
            d0 += wd[c] * x0.x + wd[c + 1] * x0.y + wd[c + 2] * x0.z + wd[c + 3] * x0.w;
            d1 += wd[c] * x1.x + wd[c + 1] * x1.y + wd[c + 2] * x1.z + wd[c + 3] * x1.w;
            d2 += wd[c] * x2.x + wd[c + 1] * x2.y + wd[c + 2] * x2.z + wd[c + 3] * x2.w;
        }
        float dot = q0 * d0 + q1 * d1 + q2 * d2;
        float dn = d0 * d0 + d1 * d1 + d2 * d2;
        float coef = (dot >= 0.f) ? 0.f : 0.8f * dot / (dn + VN_EPS);
        a0 += q0 - coef * d0;
        a1 += q1 - coef * d1;
        a2 += q2 - coef * d2;
        __syncthreads();
    }
    float s = 1.f / (float)KNN;
    size_t ob = ((size_t)(b * 64 + o) * 3) * NPTS + n;
    out[ob] = a0 * s;
    out[ob + NPTS] = a1 * s;
    out[ob + 2 * NPTS] = a2 * s;
}

// ---------------- host ----------------
extern "C" void kernel_launch(void* const* d_in, const int* in_sizes, int n_in,
                              void* d_out, int out_size, void* d_ws, size_t ws_size,
                              hipStream_t stream) {
    const float* x = (const float*)d_in[0];
    const float* W1 = (const float*)d_in[1];
    const float* Wd = (const float*)d_in[2];
    const float* gamma = (const float*)d_in[3];
    const float* beta = (const float*)d_in[4];
    float* out = (float*)d_out;

    char* ws = (char*)d_ws;
    size_t off = 0;
    auto alloc = [&](size_t bytes) {
        void* p = ws + off;
        off = (off + bytes + 255) & ~(size_t)255;
        return p;
    };
    float* xxp = (float*)alloc((size_t)NB * NPTS * 4);
    int* idxp = (int*)alloc((size_t)NB * NPTS * KNN * 4);
    float* up = (float*)alloc((size_t)NB * NPTS * 192 * 4);
    float* vp = (float*)alloc((size_t)NB * NPTS * 192 * 4);
    float* partial = (float*)alloc((size_t)2048 * 128 * 4);
    float* gsbs = (float*)alloc(512);
    float* dbuf = (float*)(ws + off);

    const int totalRows = NB * NPTS;                 // 16384
    long avail = (long)ws_size - (long)off;
    long cap_l = avail / ((long)NPTS * 4);
    int cap = (int)((cap_l / 64) * 64);
    if (cap < 64) cap = 64;
    if (cap > totalRows) cap = totalRows;

    k_xx<<<totalRows / 256, 256, 0, stream>>>(x, xxp);

    for (int start = 0; start < totalRows; start += cap) {
        int rows = totalRows - start;
        if (rows > cap) rows = cap;
        dim3 gg(rows / 64, NPTS / 64);
        k_dist<<<gg, 256, 0, stream>>>(x, xxp, dbuf, start);
        k_topk<<<rows, 256, 0, stream>>>(dbuf, idxp, start);
    }

    k_uv<<<totalRows / 16, 256, 0, stream>>>(x, W1, up, vp);
    k_stats<<<totalRows / 8, 256, 0, stream>>>(up, vp, idxp, partial);
    k_reduce<<<64, 256, 0, stream>>>(partial, gamma, beta, gsbs);
    k_final<<<totalRows / 4, 256, 0, stream>>>(up, vp, idxp, Wd, gsbs, out);
}

// Round 3
// 1009.122 us; speedup vs baseline: 1.2383x; 1.2383x over previous
//
#include <hip/hip_runtime.h>
#include <math.h>

#define NPTS 8192
#define NB 2
#define FDIM 96
#define KNN 20
#define VN_EPS 1e-6f
#define VN_BN_EPS 1e-5f

typedef float f32x16 __attribute__((ext_vector_type(16)));
typedef _Float16 f16x8 __attribute__((ext_vector_type(8)));
typedef unsigned short u16x8 __attribute__((ext_vector_type(8)));

// drain LDS ops then stop compiler motion across this point (waves are independent;
// no cross-wave sync needed — one point per wave)
#define WAVESYNC()                                            \
    do {                                                      \
        asm volatile("s_waitcnt lgkmcnt(0)" ::: "memory");    \
        __builtin_amdgcn_wave_barrier();                      \
        asm volatile("" ::: "memory");                        \
    } while (0)

// ---------------- Kernel 1: xx = sum_f xf^2  AND  xs = f16 split table ----------------
// xs layout: [b*N + n][ hi f16 x96 | lo f16 x96 ]  (384 B per point)
__global__ __launch_bounds__(256) void k_prep(const float* __restrict__ x,
                                              float* __restrict__ xx,
                                              unsigned short* __restrict__ xs) {
    int m = blockIdx.x * 256 + threadIdx.x;       // global point b*N+n
    int b = m >> 13, n = m & 8191;
    const float* xf = x + (size_t)b * FDIM * NPTS;
    unsigned short* row = xs + (size_t)m * 192;
    float s = 0.f;
    for (int fc = 0; fc < 12; ++fc) {
        u16x8 hv, lv;
        #pragma unroll
        for (int j = 0; j < 8; ++j) {
            float vv = xf[(size_t)(fc * 8 + j) * NPTS + n];
            s += vv * vv;
            _Float16 h = (_Float16)vv;
            float hf = (float)h;
            _Float16 l = (_Float16)(vv - hf);
            union { _Float16 f; unsigned short u; } ch, cl;
            ch.f = h; cl.f = l;
            hv[j] = ch.u; lv[j] = cl.u;
        }
        *(u16x8*)(row + fc * 8) = hv;
        *(u16x8*)(row + 96 + fc * 8) = lv;
    }
    xx[m] = s;
}

// ---------------- Kernel 2: neg-dist via MFMA, 3-pass f16 split ----------------
// dot' = hA*hB + hA*lB + lA*hB  (error ~2^-22 rel; lo*lo dropped)
// dbuf[localRow][m] = 2*dot' - xx[n] - xx[m]
__global__ __launch_bounds__(512) void k_dist(const unsigned short* __restrict__ xs,
                                              const float* __restrict__ xx,
                                              float* __restrict__ dbuf,
                                              int rowStart) {
    __shared__ __align__(16) unsigned short Asl[256][104];
    __shared__ __align__(16) unsigned short Bsl[256][104];
    __shared__ float sxr[256];
    __shared__ float sxc[256];
    int t = threadIdx.x;
    int row0 = rowStart + blockIdx.x * 256;       // global row b*N+n
    int b = row0 >> 13, n0 = row0 & 8191;
    int m0 = blockIdx.y * 256;
    const unsigned short* xsb = xs + (size_t)b * NPTS * 192;
    int lane = t & 63, wid = t >> 6;              // 8 waves: 2 row x 4 col
    int wrow = wid >> 2, wcol = wid & 3;
    int l31 = lane & 31, hi = lane >> 5;
    f32x16 acc[4][2];
    #pragma unroll
    for (int rt = 0; rt < 4; ++rt)
        #pragma unroll
        for (int ct = 0; ct < 2; ++ct)
            #pragma unroll
            for (int e = 0; e < 16; ++e) acc[rt][ct][e] = 0.f;

    int sp = t >> 1, sh = t & 1;
    auto stageA = [&](int part) {
        const unsigned short* sa = xsb + (size_t)(n0 + sp) * 192 + part * 96 + sh * 48;
        unsigned short* da = &Asl[sp][sh * 48];
        #pragma unroll
        for (int j = 0; j < 6; ++j) *(u16x8*)(da + j * 8) = *(const u16x8*)(sa + j * 8);
    };
    auto stageB = [&](int part) {
        const unsigned short* sb = xsb + (size_t)(m0 + sp) * 192 + part * 96 + sh * 48;
        unsigned short* db = &Bsl[sp][sh * 48];
        #pragma unroll
        for (int j = 0; j < 6; ++j) *(u16x8*)(db + j * 8) = *(const u16x8*)(sb + j * 8);
    };
    auto mmpass = [&]() {
        #pragma unroll
        for (int ks = 0; ks < 6; ++ks) {
            f16x8 af[4], bfr[2];
            #pragma unroll
            for (int rt = 0; rt < 4; ++rt)
                af[rt] = *(const f16x8*)&Asl[wrow * 128 + rt * 32 + l31][ks * 16 + hi * 8];
            #pragma unroll
            for (int ct = 0; ct < 2; ++ct)
                bfr[ct] = *(const f16x8*)&Bsl[wcol * 64 + ct * 32 + l31][ks * 16 + hi * 8];
            #pragma unroll
            for (int rt = 0; rt < 4; ++rt)
                #pragma unroll
                for (int ct = 0; ct < 2; ++ct)
                    acc[rt][ct] = __builtin_amdgcn_mfma_f32_32x32x16_f16(af[rt], bfr[ct], acc[rt][ct], 0, 0, 0);
        }
    };

    stageA(0); stageB(0);        // hA, hB
    __syncthreads();
    mmpass();                    // hA*hB
    __syncthreads();
    stageB(1);                   // lB
    __syncthreads();
    mmpass();                    // hA*lB
    __syncthreads();
    stageA(1); stageB(0);        // lA, hB
    __syncthreads();
    mmpass();                    // lA*hB

    __syncthreads();
    if (t < 256) sxr[t] = xx[row0 + t];
    else sxc[t - 256] = xx[(b << 13) + m0 + (t - 256)];
    __syncthreads();
    int lrow0 = row0 - rowStart;
    #pragma unroll
    for (int rt = 0; rt < 4; ++rt) {
        #pragma unroll
        for (int ct = 0; ct < 2; ++ct) {
            int colg = wcol * 64 + ct * 32 + l31;
            float xcv = sxc[colg];
            #pragma unroll
            for (int q = 0; q < 4; ++q) {
                int rbase = wrow * 128 + rt * 32 + 4 * hi + 8 * q;
                #pragma unroll
                for (int r = 0; r < 4; ++r) {
                    float valx = 2.f * acc[rt][ct][q * 4 + r] - sxr[rbase + r] - xcv;
                    dbuf[(size_t)(lrow0 + rbase + r) * NPTS + m0 + colg] = valx;
                }
            }
        }
    }
}

// ---------------- Kernel 3: top-20 per row (iterative extraction) ----------------
__global__ __launch_bounds__(256) void k_topk(const float* __restrict__ dbuf,
                                              int* __restrict__ idxOut,
                                              int rowStart) {
    int r = blockIdx.x;
    const float* row = dbuf + (size_t)r * NPTS;
    int t = threadIdx.x;
    float vals[32];
    #pragma unroll
    for (int i = 0; i < 32; ++i) vals[i] = row[t + (i << 8)];
    unsigned taken = 0u;
    float bv = -3.4e38f;
    int bi = 0x7fffffff;
    for (int i = 0; i < 32; ++i) {
        float vv = vals[i];
        if (vv > bv) { bv = vv; bi = t + (i << 8); }
    }
    __shared__ float swv[4];
    __shared__ int swi[4];
    __shared__ int sbi;
    int grow = rowStart + r;
    for (int kk = 0; kk < KNN; ++kk) {
        float rv = bv;
        int ri = bi;
        #pragma unroll
        for (int off = 1; off < 64; off <<= 1) {
            float ov = __shfl_xor(rv, off);
            int oi = __shfl_xor(ri, off);
            if (ov > rv || (ov == rv && oi < ri)) { rv = ov; ri = oi; }
        }
        if ((t & 63) == 0) { swv[t >> 6] = rv; swi[t >> 6] = ri; }
        __syncthreads();
        if (t == 0) {
            float fv = swv[0]; int fi = swi[0];
            #pragma unroll
            for (int w = 1; w < 4; ++w) {
                if (swv[w] > fv || (swv[w] == fv && swi[w] < fi)) { fv = swv[w]; fi = swi[w]; }
            }
            idxOut[(size_t)grow * KNN + kk] = fi;
            sbi = fi;
        }
        __syncthreads();
        int win = sbi;
        __syncthreads();
        if ((win & 255) == t) {
            taken |= 1u << (win >> 8);
            bv = -3.4e38f; bi = 0x7fffffff;
            for (int i = 0; i < 32; ++i) {
                if ((taken >> i) & 1u) continue;
                float vv = vals[i];
                if (vv > bv) { bv = vv; bi = t + (i << 8); }
            }
        }
    }
}

// ---------------- Kernel 4: u = A*x_point, v = (B-A)*x_point ----------------
__global__ __launch_bounds__(256) void k_uv(const float* __restrict__ x,
                                            const float* __restrict__ W1,
                                            float* __restrict__ u,
                                            float* __restrict__ v) {
    __shared__ float sA[64 * 33];
    __shared__ float sV[64 * 33];
    __shared__ float sxf[FDIM * 16];
    int t = threadIdx.x;
    for (int i = t; i < 64 * 32; i += 256) {
        int o = i >> 5, c = i & 31;
        float a = W1[o * 64 + c];
        sA[o * 33 + c] = a;
        sV[o * 33 + c] = W1[o * 64 + 32 + c] - a;
    }
    int p0 = blockIdx.x * 16;
    int b = p0 >> 13, nb = p0 & 8191;
    const float* xf = x + (size_t)b * FDIM * NPTS;
    for (int i = t; i < FDIM * 16; i += 256) {
        int f = i >> 4, p = i & 15;
        sxf[f * 16 + p] = xf[(size_t)f * NPTS + nb + p];
    }
    __syncthreads();
    #pragma unroll
    for (int ii = 0; ii < 4; ++ii) {
        int it = t + 256 * ii;
        int o = it & 63, p = it >> 6;
        float u0 = 0.f, u1 = 0.f, u2 = 0.f, w0 = 0.f, w1 = 0.f, w2 = 0.f;
        #pragma unroll
        for (int c = 0; c < 32; ++c) {
            float a = sA[o * 33 + c];
            float wv = sV[o * 33 + c];
            float x0 = sxf[(c * 3 + 0) * 16 + p];
            float x1 = sxf[(c * 3 + 1) * 16 + p];
            float x2 = sxf[(c * 3 + 2) * 16 + p];
            u0 += a * x0;  u1 += a * x1;  u2 += a * x2;
            w0 += wv * x0; w1 += wv * x1; w2 += wv * x2;
        }
        size_t base = ((size_t)(p0 + p) * 64 + o) * 3;
        u[base] = u0; u[base + 1] = u1; u[base + 2] = u2;
        v[base] = w0; v[base + 1] = w1; v[base + 2] = w2;
    }
}

// ---------------- Kernel 5: BN stats partials (8 points/block) ----------------
__global__ __launch_bounds__(256) void k_stats(const float* __restrict__ u,
                                               const float* __restrict__ v,
                                               const int* __restrict__ idx,
                                               float* __restrict__ partial) {
    int blk = blockIdx.x, t = threadIdx.x;
    int o = t & 63, sub = t >> 6;
    int p0 = blk * 8;
    __shared__ float svf[8 * 192];
    __shared__ int sjf[8 * KNN];
    for (int i = t; i < 8 * 192; i += 256) svf[i] = v[(size_t)p0 * 192 + i];
    for (int i = t; i < 8 * KNN; i += 256) sjf[i] = idx[(size_t)p0 * KNN + i];
    __syncthreads();
    float s1 = 0.f, s2 = 0.f;
    for (int p = 0; p < 8; ++p) {
        int gpt = p0 + p;
        size_t ubase = (size_t)(gpt >> 13) * NPTS * 192;
        const float* vp = &svf[p * 192 + o * 3];
        float v0 = vp[0], v1 = vp[1], v2 = vp[2];
        for (int kk = sub; kk < KNN; kk += 4) {
            int j = sjf[p * KNN + kk];
            const float* up = u + ubase + (size_t)j * 192 + o * 3;
            float q0 = up[0] + v0, q1 = up[1] + v1, q2 = up[2] + v2;
            float nrm = sqrtf(q0 * q0 + q1 * q1 + q2 * q2) + VN_EPS;
            s1 += nrm;
            s2 += nrm * nrm;
        }
    }
    __shared__ float r1[256], r2[256];
    r1[t] = s1; r2[t] = s2;
    __syncthreads();
    if (t < 64) {
        float a1 = r1[t] + r1[t + 64] + r1[t + 128] + r1[t + 192];
        float a2 = r2[t] + r2[t + 64] + r2[t + 128] + r2[t + 192];
        partial[(size_t)blk * 128 + t] = a1;
        partial[(size_t)blk * 128 + 64 + t] = a2;
    }
}

// ---------------- Kernel 6: reduce stats -> gs, bs ----------------
__global__ __launch_bounds__(256) void k_reduce(const float* __restrict__ partial,
                                                const float* __restrict__ gamma,
                                                const float* __restrict__ beta,
                                                float* __restrict__ gsbs) {
    int ch = blockIdx.x, t = threadIdx.x;
    float s1 = 0.f, s2 = 0.f;
    for (int i = t; i < 2048; i += 256) {
        s1 += partial[(size_t)i * 128 + ch];
        s2 += partial[(size_t)i * 128 + 64 + ch];
    }
    __shared__ float r1[256], r2[256];
    r1[t] = s1; r2[t] = s2;
    __syncthreads();
    for (int s = 128; s > 0; s >>= 1) {
        if (t < s) { r1[t] += r1[t + s]; r2[t] += r2[t + s]; }
        __syncthreads();
    }
    if (t == 0) {
        const float cnt = (float)(NB * NPTS * KNN);
        float mean = r1[0] / cnt;
        float var = r2[0] / cnt - mean * mean;
        float inv = 1.0f / sqrtf(var + VN_BN_EPS);
        float g = gamma[ch] * inv;
        gsbs[ch] = g;
        gsbs[64 + ch] = beta[ch] - mean * g;
    }
}

// ---------------- Kernel 7: fused BN + VN-LeakyReLU + mean over k ----------------
// full fp32; one wave per point -> wave-local sync only (no block barriers)
__global__ __launch_bounds__(256) void k_final(const float* __restrict__ u,
                                               const float* __restrict__ v,
                                               const int* __restrict__ idx,
                                               const float* __restrict__ Wd,
                                               const float* __restrict__ gsbs,
                                               float* __restrict__ out) {
    int t = threadIdx.x;
    int o = t & 63, w = t >> 6;
    int gpt = blockIdx.x * 4 + w;                 // global point b*N+n
    int b = gpt >> 13, n = gpt & 8191;
    float wd[64];
    #pragma unroll
    for (int c = 0; c < 64; ++c) wd[c] = Wd[o * 64 + c];
    float gso = gsbs[o], bso = gsbs[64 + o];
    __shared__ __align__(16) float spb[4][3 * 64];
    size_t vb = (size_t)gpt * 192 + o * 3;
    float v0 = v[vb], v1 = v[vb + 1], v2 = v[vb + 2];
    const int* jrow = idx + (size_t)gpt * KNN;
    size_t ubase = (size_t)b * NPTS * 192;
    float a0 = 0.f, a1 = 0.f, a2 = 0.f;
    for (int kk = 0; kk < KNN; ++kk) {
        int j = jrow[kk];
        const float* up = u + ubase + (size_t)j * 192 + o * 3;
        float q0 = up[0] + v0, q1 = up[1] + v1, q2 = up[2] + v2;
        float nrm = sqrtf(q0 * q0 + q1 * q1 + q2 * q2) + VN_EPS;
        float f = (gso * nrm + bso) / nrm;
        q0 *= f; q1 *= f; q2 *= f;
        spb[w][o] = q0;
        spb[w][64 + o] = q1;
        spb[w][128 + o] = q2;
        WAVESYNC();
        float d0 = 0.f, d1 = 0.f, d2 = 0.f;
        #pragma unroll
        for (int c = 0; c < 64; c += 4) {
            float4 x0 = *(const float4*)&spb[w][c];
            float4 x1 = *(const float4*)&spb[w][64 + c];
            float4 x2 = *(const float4*)&spb[w][128 + c];
            d0 += wd[c] * x0.x + wd[c + 1] * x0.y + wd[c + 2] * x0.z + wd[c + 3] * x0.w;
            d1 += wd[c] * x1.x + wd[c + 1] * x1.y + wd[c + 2] * x1.z + wd[c + 3] * x1.w;
            d2 += wd[c] * x2.x + wd[c + 1] * x2.y + wd[c + 2] * x2.z + wd[c + 3] * x2.w;
        }
        WAVESYNC();
        float dot = q0 * d0 + q1 * d1 + q2 * d2;
        float dn = d0 * d0 + d1 * d1 + d2 * d2;
        float coef = (dot >= 0.f) ? 0.f : 0.8f * dot / (dn + VN_EPS);
        a0 += q0 - coef * d0;
        a1 += q1 - coef * d1;
        a2 += q2 - coef * d2;
    }
    float s = 1.f / (float)KNN;
    size_t ob = ((size_t)(b * 64 + o) * 3) * NPTS + n;
    out[ob] = a0 * s;
    out[ob + NPTS] = a1 * s;
    out[ob + 2 * NPTS] = a2 * s;
}

// ---------------- host ----------------
extern "C" void kernel_launch(void* const* d_in, const int* in_sizes, int n_in,
                              void* d_out, int out_size, void* d_ws, size_t ws_size,
                              hipStream_t stream) {
    const float* x = (const float*)d_in[0];
    const float* W1 = (const float*)d_in[1];
    const float* Wd = (const float*)d_in[2];
    const float* gamma = (const float*)d_in[3];
    const float* beta = (const float*)d_in[4];
    float* out = (float*)d_out;

    char* ws = (char*)d_ws;
    size_t off = 0;
    auto alloc = [&](size_t bytes) {
        void* p = ws + off;
        off = (off + bytes + 255) & ~(size_t)255;
        return p;
    };
    float* xxp = (float*)alloc((size_t)NB * NPTS * 4);
    int* idxp = (int*)alloc((size_t)NB * NPTS * KNN * 4);
    float* up = (float*)alloc((size_t)NB * NPTS * 192 * 4);
    float* vp = (float*)alloc((size_t)NB * NPTS * 192 * 4);
    float* partial = (float*)alloc((size_t)2048 * 128 * 4);
    float* gsbs = (float*)alloc(512);
    unsigned short* xsp = (unsigned short*)alloc((size_t)NB * NPTS * 192 * 2);
    float* dbuf = (float*)(ws + off);

    const int totalRows = NB * NPTS;                 // 16384
    long avail = (long)ws_size - (long)off;
    long cap_l = avail / ((long)NPTS * 4);
    int cap = (int)((cap_l / 256) * 256);
    if (cap < 256) cap = 256;
    if (cap > totalRows) cap = totalRows;

    k_prep<<<totalRows / 256, 256, 0, stream>>>(x, xxp, xsp);

    for (int start = 0; start < totalRows; start += cap) {
        int rows = totalRows - start;
        if (rows > cap) rows = cap;
        dim3 gg(rows / 256, NPTS / 256);
        k_dist<<<gg, 512, 0, stream>>>(xsp, xxp, dbuf, start);
        k_topk<<<rows, 256, 0, stream>>>(dbuf, idxp, start);
    }

    k_uv<<<totalRows / 16, 256, 0, stream>>>(x, W1, up, vp);
    k_stats<<<totalRows / 8, 256, 0, stream>>>(up, vp, idxp, partial);
    k_reduce<<<64, 256, 0, stream>>>(partial, gamma, beta, gsbs);
    k_final<<<totalRows / 4, 256, 0, stream>>>(up, vp, idxp, Wd, gsbs, out);
}

// Round 4
// 886.565 us; speedup vs baseline: 1.4095x; 1.1382x over previous
//
#include <hip/hip_runtime.h>
#include <math.h>

#define NPTS 8192
#define NB 2
#define FDIM 96
#define KNN 20
#define VN_EPS 1e-6f
#define VN_BN_EPS 1e-5f

typedef float f32x16 __attribute__((ext_vector_type(16)));
typedef _Float16 f16x8 __attribute__((ext_vector_type(8)));
typedef unsigned short u16x8 __attribute__((ext_vector_type(8)));

// drain LDS ops + compiler barrier (waves independent; no cross-wave sync needed)
#define WAVESYNC()                                            \
    do {                                                      \
        asm volatile("s_waitcnt lgkmcnt(0)" ::: "memory");    \
        __builtin_amdgcn_wave_barrier();                      \
        asm volatile("" ::: "memory");                        \
    } while (0)

// ---------------- Kernel 1: xx = sum_f xf^2  AND  xs = f16 split table ----------------
__global__ __launch_bounds__(256) void k_prep(const float* __restrict__ x,
                                              float* __restrict__ xx,
                                              unsigned short* __restrict__ xs) {
    int m = blockIdx.x * 256 + threadIdx.x;
    int b = m >> 13, n = m & 8191;
    const float* xf = x + (size_t)b * FDIM * NPTS;
    unsigned short* row = xs + (size_t)m * 192;
    float s = 0.f;
    for (int fc = 0; fc < 12; ++fc) {
        u16x8 hv, lv;
        #pragma unroll
        for (int j = 0; j < 8; ++j) {
            float vv = xf[(size_t)(fc * 8 + j) * NPTS + n];
            s += vv * vv;
            _Float16 h = (_Float16)vv;
            float hf = (float)h;
            _Float16 l = (_Float16)(vv - hf);
            union { _Float16 f; unsigned short u; } ch, cl;
            ch.f = h; cl.f = l;
            hv[j] = ch.u; lv[j] = cl.u;
        }
        *(u16x8*)(row + fc * 8) = hv;
        *(u16x8*)(row + 96 + fc * 8) = lv;
    }
    xx[m] = s;
}

// ---------------- Kernel 2: neg-dist via MFMA, 3-pass f16 split ----------------
__global__ __launch_bounds__(512) void k_dist(const unsigned short* __restrict__ xs,
                                              const float* __restrict__ xx,
                                              float* __restrict__ dbuf,
                                              int rowStart) {
    __shared__ __align__(16) unsigned short Asl[256][104];
    __shared__ __align__(16) unsigned short Bsl[256][104];
    __shared__ float sxr[256];
    __shared__ float sxc[256];
    int t = threadIdx.x;
    int row0 = rowStart + blockIdx.x * 256;
    int b = row0 >> 13, n0 = row0 & 8191;
    int m0 = blockIdx.y * 256;
    const unsigned short* xsb = xs + (size_t)b * NPTS * 192;
    int lane = t & 63, wid = t >> 6;
    int wrow = wid >> 2, wcol = wid & 3;
    int l31 = lane & 31, hi = lane >> 5;
    f32x16 acc[4][2];
    #pragma unroll
    for (int rt = 0; rt < 4; ++rt)
        #pragma unroll
        for (int ct = 0; ct < 2; ++ct)
            #pragma unroll
            for (int e = 0; e < 16; ++e) acc[rt][ct][e] = 0.f;

    int sp = t >> 1, sh = t & 1;
    auto stageA = [&](int part) {
        const unsigned short* sa = xsb + (size_t)(n0 + sp) * 192 + part * 96 + sh * 48;
        unsigned short* da = &Asl[sp][sh * 48];
        #pragma unroll
        for (int j = 0; j < 6; ++j) *(u16x8*)(da + j * 8) = *(const u16x8*)(sa + j * 8);
    };
    auto stageB = [&](int part) {
        const unsigned short* sb = xsb + (size_t)(m0 + sp) * 192 + part * 96 + sh * 48;
        unsigned short* db = &Bsl[sp][sh * 48];
        #pragma unroll
        for (int j = 0; j < 6; ++j) *(u16x8*)(db + j * 8) = *(const u16x8*)(sb + j * 8);
    };
    auto mmpass = [&]() {
        #pragma unroll
        for (int ks = 0; ks < 6; ++ks) {
            f16x8 af[4], bfr[2];
            #pragma unroll
            for (int rt = 0; rt < 4; ++rt)
                af[rt] = *(const f16x8*)&Asl[wrow * 128 + rt * 32 + l31][ks * 16 + hi * 8];
            #pragma unroll
            for (int ct = 0; ct < 2; ++ct)
                bfr[ct] = *(const f16x8*)&Bsl[wcol * 64 + ct * 32 + l31][ks * 16 + hi * 8];
            #pragma unroll
            for (int rt = 0; rt < 4; ++rt)
                #pragma unroll
                for (int ct = 0; ct < 2; ++ct)
                    acc[rt][ct] = __builtin_amdgcn_mfma_f32_32x32x16_f16(af[rt], bfr[ct], acc[rt][ct], 0, 0, 0);
        }
    };

    stageA(0); stageB(0);
    __syncthreads();
    mmpass();                    // hA*hB
    __syncthreads();
    stageB(1);
    __syncthreads();
    mmpass();                    // hA*lB
    __syncthreads();
    stageA(1); stageB(0);
    __syncthreads();
    mmpass();                    // lA*hB

    __syncthreads();
    if (t < 256) sxr[t] = xx[row0 + t];
    else sxc[t - 256] = xx[(b << 13) + m0 + (t - 256)];
    __syncthreads();
    int lrow0 = row0 - rowStart;
    #pragma unroll
    for (int rt = 0; rt < 4; ++rt) {
        #pragma unroll
        for (int ct = 0; ct < 2; ++ct) {
            int colg = wcol * 64 + ct * 32 + l31;
            float xcv = sxc[colg];
            #pragma unroll
            for (int q = 0; q < 4; ++q) {
                int rbase = wrow * 128 + rt * 32 + 4 * hi + 8 * q;
                #pragma unroll
                for (int r = 0; r < 4; ++r) {
                    float valx = 2.f * acc[rt][ct][q * 4 + r] - sxr[rbase + r] - xcv;
                    dbuf[(size_t)(lrow0 + rbase + r) * NPTS + m0 + colg] = valx;
                }
            }
        }
    }
}

// ---------------- Kernel 3: top-20 per row ----------------
__global__ __launch_bounds__(256) void k_topk(const float* __restrict__ dbuf,
                                              int* __restrict__ idxOut,
                                              int rowStart) {
    int r = blockIdx.x;
    const float* row = dbuf + (size_t)r * NPTS;
    int t = threadIdx.x;
    float vals[32];
    #pragma unroll
    for (int i = 0; i < 32; ++i) vals[i] = row[t + (i << 8)];
    unsigned taken = 0u;
    float bv = -3.4e38f;
    int bi = 0x7fffffff;
    for (int i = 0; i < 32; ++i) {
        float vv = vals[i];
        if (vv > bv) { bv = vv; bi = t + (i << 8); }
    }
    __shared__ float swv[4];
    __shared__ int swi[4];
    __shared__ int sbi;
    int grow = rowStart + r;
    for (int kk = 0; kk < KNN; ++kk) {
        float rv = bv;
        int ri = bi;
        #pragma unroll
        for (int off = 1; off < 64; off <<= 1) {
            float ov = __shfl_xor(rv, off);
            int oi = __shfl_xor(ri, off);
            if (ov > rv || (ov == rv && oi < ri)) { rv = ov; ri = oi; }
        }
        if ((t & 63) == 0) { swv[t >> 6] = rv; swi[t >> 6] = ri; }
        __syncthreads();
        if (t == 0) {
            float fv = swv[0]; int fi = swi[0];
            #pragma unroll
            for (int w = 1; w < 4; ++w) {
                if (swv[w] > fv || (swv[w] == fv && swi[w] < fi)) { fv = swv[w]; fi = swi[w]; }
            }
            idxOut[(size_t)grow * KNN + kk] = fi;
            sbi = fi;
        }
        __syncthreads();
        int win = sbi;
        __syncthreads();
        if ((win & 255) == t) {
            taken |= 1u << (win >> 8);
            bv = -3.4e38f; bi = 0x7fffffff;
            for (int i = 0; i < 32; ++i) {
                if ((taken >> i) & 1u) continue;
                float vv = vals[i];
                if (vv > bv) { bv = vv; bi = t + (i << 8); }
            }
        }
    }
}

// ---------------- Kernel 4: u = A*x_point, v = (B-A)*x_point ----------------
__global__ __launch_bounds__(256) void k_uv(const float* __restrict__ x,
                                            const float* __restrict__ W1,
                                            float* __restrict__ u,
                                            float* __restrict__ v) {
    __shared__ float sA[64 * 33];
    __shared__ float sV[64 * 33];
    __shared__ float sxf[FDIM * 16];
    int t = threadIdx.x;
    for (int i = t; i < 64 * 32; i += 256) {
        int o = i >> 5, c = i & 31;
        float a = W1[o * 64 + c];
        sA[o * 33 + c] = a;
        sV[o * 33 + c] = W1[o * 64 + 32 + c] - a;
    }
    int p0 = blockIdx.x * 16;
    int b = p0 >> 13, nb = p0 & 8191;
    const float* xf = x + (size_t)b * FDIM * NPTS;
    for (int i = t; i < FDIM * 16; i += 256) {
        int f = i >> 4, p = i & 15;
        sxf[f * 16 + p] = xf[(size_t)f * NPTS + nb + p];
    }
    __syncthreads();
    #pragma unroll
    for (int ii = 0; ii < 4; ++ii) {
        int it = t + 256 * ii;
        int o = it & 63, p = it >> 6;
        float u0 = 0.f, u1 = 0.f, u2 = 0.f, w0 = 0.f, w1 = 0.f, w2 = 0.f;
        #pragma unroll
        for (int c = 0; c < 32; ++c) {
            float a = sA[o * 33 + c];
            float wv = sV[o * 33 + c];
            float x0 = sxf[(c * 3 + 0) * 16 + p];
            float x1 = sxf[(c * 3 + 1) * 16 + p];
            float x2 = sxf[(c * 3 + 2) * 16 + p];
            u0 += a * x0;  u1 += a * x1;  u2 += a * x2;
            w0 += wv * x0; w1 += wv * x1; w2 += wv * x2;
        }
        size_t base = ((size_t)(p0 + p) * 64 + o) * 3;
        u[base] = u0; u[base + 1] = u1; u[base + 2] = u2;
        v[base] = w0; v[base + 1] = w1; v[base + 2] = w2;
    }
}

// ---------------- Kernel 5: BN stats partials ----------------
__global__ __launch_bounds__(256) void k_stats(const float* __restrict__ u,
                                               const float* __restrict__ v,
                                               const int* __restrict__ idx,
                                               float* __restrict__ partial) {
    int blk = blockIdx.x, t = threadIdx.x;
    int o = t & 63, sub = t >> 6;
    int p0 = blk * 8;
    __shared__ float svf[8 * 192];
    __shared__ int sjf[8 * KNN];
    for (int i = t; i < 8 * 192; i += 256) svf[i] = v[(size_t)p0 * 192 + i];
    for (int i = t; i < 8 * KNN; i += 256) sjf[i] = idx[(size_t)p0 * KNN + i];
    __syncthreads();
    float s1 = 0.f, s2 = 0.f;
    for (int p = 0; p < 8; ++p) {
        int gpt = p0 + p;
        size_t ubase = (size_t)(gpt >> 13) * NPTS * 192;
        const float* vp = &svf[p * 192 + o * 3];
        float v0 = vp[0], v1 = vp[1], v2 = vp[2];
        for (int kk = sub; kk < KNN; kk += 4) {
            int j = sjf[p * KNN + kk];
            const float* up = u + ubase + (size_t)j * 192 + o * 3;
            float q0 = up[0] + v0, q1 = up[1] + v1, q2 = up[2] + v2;
            float nrm = sqrtf(q0 * q0 + q1 * q1 + q2 * q2) + VN_EPS;
            s1 += nrm;
            s2 += nrm * nrm;
        }
    }
    __shared__ float r1[256], r2[256];
    r1[t] = s1; r2[t] = s2;
    __syncthreads();
    if (t < 64) {
        float a1 = r1[t] + r1[t + 64] + r1[t + 128] + r1[t + 192];
        float a2 = r2[t] + r2[t + 64] + r2[t + 128] + r2[t + 192];
        partial[(size_t)blk * 128 + t] = a1;
        partial[(size_t)blk * 128 + 64 + t] = a2;
    }
}

// ---------------- Kernel 6: reduce stats -> gs, bs ----------------
__global__ __launch_bounds__(256) void k_reduce(const float* __restrict__ partial,
                                                const float* __restrict__ gamma,
                                                const float* __restrict__ beta,
                                                float* __restrict__ gsbs) {
    int ch = blockIdx.x, t = threadIdx.x;
    float s1 = 0.f, s2 = 0.f;
    for (int i = t; i < 2048; i += 256) {
        s1 += partial[(size_t)i * 128 + ch];
        s2 += partial[(size_t)i * 128 + 64 + ch];
    }
    __shared__ float r1[256], r2[256];
    r1[t] = s1; r2[t] = s2;
    __syncthreads();
    for (int s = 128; s > 0; s >>= 1) {
        if (t < s) { r1[t] += r1[t + s]; r2[t] += r2[t + s]; }
        __syncthreads();
    }
    if (t == 0) {
        const float cnt = (float)(NB * NPTS * KNN);
        float mean = r1[0] / cnt;
        float var = r2[0] / cnt - mean * mean;
        float inv = 1.0f / sqrtf(var + VN_BN_EPS);
        float g = gamma[ch] * inv;
        gsbs[ch] = g;
        gsbs[64 + ch] = beta[ch] - mean * g;
    }
}

// ---------------- Kernel 7: fused BN + VN-LeakyReLU + mean, MFMA matvec ----------------
// One wave per point. Per half (10 k): build Q (lane=channel) -> LDS f16 [col][72],
// C = Q^T * Wd^T via 8 mfma_f32_32x32x16_f16 (M=30 cols=(k,dim), N=64=o, K=64=c),
// D scattered to LDS f32 [row][64], then elementwise post (lane=o).
__global__ __launch_bounds__(256) void k_final(const float* __restrict__ u,
                                               const float* __restrict__ v,
                                               const int* __restrict__ idx,
                                               const float* __restrict__ Wd,
                                               const float* __restrict__ gsbs,
                                               float* __restrict__ out) {
    int t = threadIdx.x;
    int lane = t & 63, w = t >> 6;
    int l31 = lane & 31, hi = lane >> 5;
    int gpt = blockIdx.x * 4 + w;                 // global point b*N+n
    int b = gpt >> 13, n = gpt & 8191;

    __shared__ __align__(16) unsigned short Qls[4][30 * 72];  // f16, stride 72 (144B, 16B-aligned rows)
    __shared__ __align__(16) float Dls[4][30 * 64];           // f32
    unsigned short* Qw = Qls[w];
    float* Dw = Dls[w];

    // B-fragments: Wd^T (K=c, N=o). lane l31 = col o=ct*32+l31, elems c = ks*16+hi*8+j
    f16x8 Bf[2][4];
    #pragma unroll
    for (int ct = 0; ct < 2; ++ct)
        #pragma unroll
        for (int ks = 0; ks < 4; ++ks) {
            const float* wp = Wd + (size_t)(ct * 32 + l31) * 64 + ks * 16 + hi * 8;
            f16x8 f;
            #pragma unroll
            for (int jj = 0; jj < 8; ++jj) f[jj] = (_Float16)wp[jj];
            Bf[ct][ks] = f;
        }

    float gso = gsbs[lane], bso = gsbs[64 + lane];
    size_t vb = (size_t)gpt * 192 + lane * 3;
    float v0 = v[vb], v1 = v[vb + 1], v2 = v[vb + 2];
    const int* jrow = idx + (size_t)gpt * KNN;
    size_t ubase = (size_t)b * NPTS * 192;
    float a0 = 0.f, a1 = 0.f, a2 = 0.f;

    for (int h = 0; h < 2; ++h) {
        // ---- build Q (lane = channel c) ----
        #pragma unroll
        for (int kl = 0; kl < 10; ++kl) {
            int j = jrow[h * 10 + kl];
            const float* up = u + ubase + (size_t)j * 192 + lane * 3;
            float q0 = up[0] + v0, q1 = up[1] + v1, q2 = up[2] + v2;
            float nrm = sqrtf(q0 * q0 + q1 * q1 + q2 * q2) + VN_EPS;
            float f = (gso * nrm + bso) / nrm;
            q0 *= f; q1 *= f; q2 *= f;
            union { _Float16 f16; unsigned short u16; } c0, c1, c2;
            c0.f16 = (_Float16)q0; c1.f16 = (_Float16)q1; c2.f16 = (_Float16)q2;
            Qw[(3 * kl + 0) * 72 + lane] = c0.u16;
            Qw[(3 * kl + 1) * 72 + lane] = c1.u16;
            Qw[(3 * kl + 2) * 72 + lane] = c2.u16;
        }
        WAVESYNC();
        // ---- MFMA: C[col=(k,d)][o] = sum_c Q[c][col] * Wd[o][c] ----
        f32x16 acc[2];
        #pragma unroll
        for (int ct = 0; ct < 2; ++ct)
            #pragma unroll
            for (int e = 0; e < 16; ++e) acc[ct][e] = 0.f;
        #pragma unroll
        for (int ks = 0; ks < 4; ++ks) {
            f16x8 af = *(const f16x8*)&Qw[l31 * 72 + ks * 16 + hi * 8];
            acc[0] = __builtin_amdgcn_mfma_f32_32x32x16_f16(af, Bf[0][ks], acc[0], 0, 0, 0);
            acc[1] = __builtin_amdgcn_mfma_f32_32x32x16_f16(af, Bf[1][ks], acc[1], 0, 0, 0);
        }
        // scatter D: row = 4*hi + 8*q + r (C-layout), col o = ct*32+l31
        #pragma unroll
        for (int ct = 0; ct < 2; ++ct)
            #pragma unroll
            for (int q = 0; q < 4; ++q)
                #pragma unroll
                for (int r = 0; r < 4; ++r) {
                    int row = 4 * hi + 8 * q + r;
                    if (row < 30) Dw[row * 64 + ct * 32 + l31] = acc[ct][q * 4 + r];
                }
        WAVESYNC();
        // ---- post (lane = o) ----
        #pragma unroll
        for (int kl = 0; kl < 10; ++kl) {
            float qd[3], dd[3];
            #pragma unroll
            for (int d = 0; d < 3; ++d) {
                union { unsigned short u16; _Float16 f16; } rr;
                rr.u16 = Qw[(3 * kl + d) * 72 + lane];
                qd[d] = (float)rr.f16;
                dd[d] = Dw[(3 * kl + d) * 64 + lane];
            }
            float dot = qd[0] * dd[0] + qd[1] * dd[1] + qd[2] * dd[2];
            float dn = dd[0] * dd[0] + dd[1] * dd[1] + dd[2] * dd[2];
            float coef = (dot >= 0.f) ? 0.f : 0.8f * dot / (dn + VN_EPS);
            a0 += qd[0] - coef * dd[0];
            a1 += qd[1] - coef * dd[1];
            a2 += qd[2] - coef * dd[2];
        }
        WAVESYNC();
    }
    float s = 1.f / (float)KNN;
    size_t ob = ((size_t)(b * 64 + lane) * 3) * NPTS + n;
    out[ob] = a0 * s;
    out[ob + NPTS] = a1 * s;
    out[ob + 2 * NPTS] = a2 * s;
}

// ---------------- host ----------------
extern "C" void kernel_launch(void* const* d_in, const int* in_sizes, int n_in,
                              void* d_out, int out_size, void* d_ws, size_t ws_size,
                              hipStream_t stream) {
    const float* x = (const float*)d_in[0];
    const float* W1 = (const float*)d_in[1];
    const float* Wd = (const float*)d_in[2];
    const float* gamma = (const float*)d_in[3];
    const float* beta = (const float*)d_in[4];
    float* out = (float*)d_out;

    char* ws = (char*)d_ws;
    size_t off = 0;
    auto alloc = [&](size_t bytes) {
        void* p = ws + off;
        off = (off + bytes + 255) & ~(size_t)255;
        return p;
    };
    float* xxp = (float*)alloc((size_t)NB * NPTS * 4);
    int* idxp = (int*)alloc((size_t)NB * NPTS * KNN * 4);
    float* up = (float*)alloc((size_t)NB * NPTS * 192 * 4);
    float* vp = (float*)alloc((size_t)NB * NPTS * 192 * 4);
    float* partial = (float*)alloc((size_t)2048 * 128 * 4);
    float* gsbs = (float*)alloc(512);
    unsigned short* xsp = (unsigned short*)alloc((size_t)NB * NPTS * 192 * 2);
    float* dbuf = (float*)(ws + off);

    const int totalRows = NB * NPTS;                 // 16384
    long avail = (long)ws_size - (long)off;
    long cap_l = avail / ((long)NPTS * 4);
    int cap = (int)((cap_l / 256) * 256);
    if (cap < 256) cap = 256;
    if (cap > 2048) cap = 2048;                      // keep chunk L3-resident (64 MB)

    k_prep<<<totalRows / 256, 256, 0, stream>>>(x, xxp, xsp);

    for (int start = 0; start < totalRows; start += cap) {
        int rows = totalRows - start;
        if (rows > cap) rows = cap;
        dim3 gg(rows / 256, NPTS / 256);
        k_dist<<<gg, 512, 0, stream>>>(xsp, xxp, dbuf, start);
        k_topk<<<rows, 256, 0, stream>>>(dbuf, idxp, start);
    }

    k_uv<<<totalRows / 16, 256, 0, stream>>>(x, W1, up, vp);
    k_stats<<<totalRows / 8, 256, 0, stream>>>(up, vp, idxp, partial);
    k_reduce<<<64, 256, 0, stream>>>(partial, gamma, beta, gsbs);
    k_final<<<totalRows / 4, 256, 0, stream>>>(up, vp, idxp, Wd, gsbs, out);
}

// Round 5
// 799.457 us; speedup vs baseline: 1.5631x; 1.1090x over previous
//
#include <hip/hip_runtime.h>
#include <math.h>

#define NPTS 8192
#define NB 2
#define FDIM 96
#define KNN 20
#define VN_EPS 1e-6f
#define VN_BN_EPS 1e-5f

typedef float f32x16 __attribute__((ext_vector_type(16)));
typedef _Float16 f16x8 __attribute__((ext_vector_type(8)));
typedef unsigned short u16x8 __attribute__((ext_vector_type(8)));

// drain LDS ops + compiler barrier (waves independent; no cross-wave sync needed)
#define WAVESYNC()                                            \
    do {                                                      \
        asm volatile("s_waitcnt lgkmcnt(0)" ::: "memory");    \
        __builtin_amdgcn_wave_barrier();                      \
        asm volatile("" ::: "memory");                        \
    } while (0)

// ---------------- Kernel 1: xx = sum_f xf^2  AND  xs = f16 split table ----------------
__global__ __launch_bounds__(256) void k_prep(const float* __restrict__ x,
                                              float* __restrict__ xx,
                                              unsigned short* __restrict__ xs) {
    int m = blockIdx.x * 256 + threadIdx.x;
    int b = m >> 13, n = m & 8191;
    const float* xf = x + (size_t)b * FDIM * NPTS;
    unsigned short* row = xs + (size_t)m * 192;
    float s = 0.f;
    for (int fc = 0; fc < 12; ++fc) {
        u16x8 hv, lv;
        #pragma unroll
        for (int j = 0; j < 8; ++j) {
            float vv = xf[(size_t)(fc * 8 + j) * NPTS + n];
            s += vv * vv;
            _Float16 h = (_Float16)vv;
            float hf = (float)h;
            _Float16 l = (_Float16)(vv - hf);
            union { _Float16 f; unsigned short u; } ch, cl;
            ch.f = h; cl.f = l;
            hv[j] = ch.u; lv[j] = cl.u;
        }
        *(u16x8*)(row + fc * 8) = hv;
        *(u16x8*)(row + 96 + fc * 8) = lv;
    }
    xx[m] = s;
}

// ---------------- Kernel 2: neg-dist via MFMA, 3-pass f16 split ----------------
// pass order hl, hh, lh -> each transition restages only ONE operand (4 stage units)
__global__ __launch_bounds__(512) void k_dist(const unsigned short* __restrict__ xs,
                                              const float* __restrict__ xx,
                                              float* __restrict__ dbuf,
                                              int rowStart) {
    __shared__ __align__(16) unsigned short Asl[256][104];
    __shared__ __align__(16) unsigned short Bsl[256][104];
    __shared__ float sxr[256];
    __shared__ float sxc[256];
    int t = threadIdx.x;
    int row0 = rowStart + blockIdx.x * 256;
    int b = row0 >> 13, n0 = row0 & 8191;
    int m0 = blockIdx.y * 256;
    const unsigned short* xsb = xs + (size_t)b * NPTS * 192;
    int lane = t & 63, wid = t >> 6;
    int wrow = wid >> 2, wcol = wid & 3;
    int l31 = lane & 31, hi = lane >> 5;
    f32x16 acc[4][2];
    #pragma unroll
    for (int rt = 0; rt < 4; ++rt)
        #pragma unroll
        for (int ct = 0; ct < 2; ++ct)
            #pragma unroll
            for (int e = 0; e < 16; ++e) acc[rt][ct][e] = 0.f;

    int sp = t >> 1, sh = t & 1;
    auto stageA = [&](int part) {
        const unsigned short* sa = xsb + (size_t)(n0 + sp) * 192 + part * 96 + sh * 48;
        unsigned short* da = &Asl[sp][sh * 48];
        #pragma unroll
        for (int j = 0; j < 6; ++j) *(u16x8*)(da + j * 8) = *(const u16x8*)(sa + j * 8);
    };
    auto stageB = [&](int part) {
        const unsigned short* sb = xsb + (size_t)(m0 + sp) * 192 + part * 96 + sh * 48;
        unsigned short* db = &Bsl[sp][sh * 48];
        #pragma unroll
        for (int j = 0; j < 6; ++j) *(u16x8*)(db + j * 8) = *(const u16x8*)(sb + j * 8);
    };
    auto mmpass = [&]() {
        #pragma unroll
        for (int ks = 0; ks < 6; ++ks) {
            f16x8 af[4], bfr[2];
            #pragma unroll
            for (int rt = 0; rt < 4; ++rt)
                af[rt] = *(const f16x8*)&Asl[wrow * 128 + rt * 32 + l31][ks * 16 + hi * 8];
            #pragma unroll
            for (int ct = 0; ct < 2; ++ct)
                bfr[ct] = *(const f16x8*)&Bsl[wcol * 64 + ct * 32 + l31][ks * 16 + hi * 8];
            #pragma unroll
            for (int rt = 0; rt < 4; ++rt)
                #pragma unroll
                for (int ct = 0; ct < 2; ++ct)
                    acc[rt][ct] = __builtin_amdgcn_mfma_f32_32x32x16_f16(af[rt], bfr[ct], acc[rt][ct], 0, 0, 0);
        }
    };

    stageA(0); stageB(1);        // Ah, Bl
    __syncthreads();
    mmpass();                    // hA*lB
    __syncthreads();
    stageB(0);                   // Bh
    __syncthreads();
    mmpass();                    // hA*hB
    __syncthreads();
    stageA(1);                   // Al   (B stays hi)
    __syncthreads();
    mmpass();                    // lA*hB

    __syncthreads();
    if (t < 256) sxr[t] = xx[row0 + t];
    else sxc[t - 256] = xx[(b << 13) + m0 + (t - 256)];
    __syncthreads();
    int lrow0 = row0 - rowStart;
    #pragma unroll
    for (int rt = 0; rt < 4; ++rt) {
        #pragma unroll
        for (int ct = 0; ct < 2; ++ct) {
            int colg = wcol * 64 + ct * 32 + l31;
            float xcv = sxc[colg];
            #pragma unroll
            for (int q = 0; q < 4; ++q) {
                int rbase = wrow * 128 + rt * 32 + 4 * hi + 8 * q;
                #pragma unroll
                for (int r = 0; r < 4; ++r) {
                    float valx = 2.f * acc[rt][ct][q * 4 + r] - sxr[rbase + r] - xcv;
                    dbuf[(size_t)(lrow0 + rbase + r) * NPTS + m0 + colg] = valx;
                }
            }
        }
    }
}

// ---------------- Kernel 3: top-20 per row, 1 barrier per extraction ----------------
__global__ __launch_bounds__(256) void k_topk(const float* __restrict__ dbuf,
                                              int* __restrict__ idxOut,
                                              int rowStart) {
    int r = blockIdx.x;
    const float* row = dbuf + (size_t)r * NPTS;
    int t = threadIdx.x;
    int lane = t & 63, w = t >> 6;
    float vals[32];
    #pragma unroll
    for (int i = 0; i < 32; ++i) vals[i] = row[t + (i << 8)];
    unsigned taken = 0u;
    float bv = -3.4e38f;
    int bi = 0x7fffffff;
    #pragma unroll
    for (int i = 0; i < 32; ++i) {
        if (vals[i] > bv) { bv = vals[i]; bi = t + (i << 8); }
    }
    __shared__ float swv[2][4];
    __shared__ int swi[2][4];
    int grow = rowStart + r;
    for (int kk = 0; kk < KNN; ++kk) {
        float rv = bv;
        int ri = bi;
        #pragma unroll
        for (int off = 1; off < 64; off <<= 1) {
            float ov = __shfl_xor(rv, off);
            int oi = __shfl_xor(ri, off);
            if (ov > rv || (ov == rv && oi < ri)) { rv = ov; ri = oi; }
        }
        int par = kk & 1;
        if (lane == 0) { swv[par][w] = rv; swi[par][w] = ri; }
        __syncthreads();
        float fv = swv[par][0];
        int fi = swi[par][0];
        #pragma unroll
        for (int ww = 1; ww < 4; ++ww) {
            float wv2 = swv[par][ww];
            int wi2 = swi[par][ww];
            if (wv2 > fv || (wv2 == fv && wi2 < fi)) { fv = wv2; fi = wi2; }
        }
        if (t == 0) idxOut[(size_t)grow * KNN + kk] = fi;
        if ((fi & 255) == t) {
            taken |= 1u << (fi >> 8);
            bv = -3.4e38f; bi = 0x7fffffff;
            #pragma unroll
            for (int i = 0; i < 32; ++i) {
                if ((taken >> i) & 1u) continue;
                if (vals[i] > bv) { bv = vals[i]; bi = t + (i << 8); }
            }
        }
    }
}

// ---------------- Kernel 4: u = A*x_point, v = (B-A)*x_point ----------------
__global__ __launch_bounds__(256) void k_uv(const float* __restrict__ x,
                                            const float* __restrict__ W1,
                                            float* __restrict__ u,
                                            float* __restrict__ v) {
    __shared__ float sA[64 * 33];
    __shared__ float sV[64 * 33];
    __shared__ float sxf[FDIM * 16];
    int t = threadIdx.x;
    for (int i = t; i < 64 * 32; i += 256) {
        int o = i >> 5, c = i & 31;
        float a = W1[o * 64 + c];
        sA[o * 33 + c] = a;
        sV[o * 33 + c] = W1[o * 64 + 32 + c] - a;
    }
    int p0 = blockIdx.x * 16;
    int b = p0 >> 13, nb = p0 & 8191;
    const float* xf = x + (size_t)b * FDIM * NPTS;
    for (int i = t; i < FDIM * 16; i += 256) {
        int f = i >> 4, p = i & 15;
        sxf[f * 16 + p] = xf[(size_t)f * NPTS + nb + p];
    }
    __syncthreads();
    #pragma unroll
    for (int ii = 0; ii < 4; ++ii) {
        int it = t + 256 * ii;
        int o = it & 63, p = it >> 6;
        float u0 = 0.f, u1 = 0.f, u2 = 0.f, w0 = 0.f, w1 = 0.f, w2 = 0.f;
        #pragma unroll
        for (int c = 0; c < 32; ++c) {
            float a = sA[o * 33 + c];
            float wv = sV[o * 33 + c];
            float x0 = sxf[(c * 3 + 0) * 16 + p];
            float x1 = sxf[(c * 3 + 1) * 16 + p];
            float x2 = sxf[(c * 3 + 2) * 16 + p];
            u0 += a * x0;  u1 += a * x1;  u2 += a * x2;
            w0 += wv * x0; w1 += wv * x1; w2 += wv * x2;
        }
        size_t base = ((size_t)(p0 + p) * 64 + o) * 3;
        u[base] = u0; u[base + 1] = u1; u[base + 2] = u2;
        v[base] = w0; v[base + 1] = w1; v[base + 2] = w2;
    }
}

// ---------------- Kernel 5: BN stats partials ----------------
__global__ __launch_bounds__(256) void k_stats(const float* __restrict__ u,
                                               const float* __restrict__ v,
                                               const int* __restrict__ idx,
                                               float* __restrict__ partial) {
    int blk = blockIdx.x, t = threadIdx.x;
    int o = t & 63, sub = t >> 6;
    int p0 = blk * 8;
    __shared__ float svf[8 * 192];
    __shared__ int sjf[8 * KNN];
    for (int i = t; i < 8 * 192; i += 256) svf[i] = v[(size_t)p0 * 192 + i];
    for (int i = t; i < 8 * KNN; i += 256) sjf[i] = idx[(size_t)p0 * KNN + i];
    __syncthreads();
    float s1 = 0.f, s2 = 0.f;
    for (int p = 0; p < 8; ++p) {
        int gpt = p0 + p;
        size_t ubase = (size_t)(gpt >> 13) * NPTS * 192;
        const float* vp = &svf[p * 192 + o * 3];
        float v0 = vp[0], v1 = vp[1], v2 = vp[2];
        for (int kk = sub; kk < KNN; kk += 4) {
            int j = sjf[p * KNN + kk];
            const float* up = u + ubase + (size_t)j * 192 + o * 3;
            float q0 = up[0] + v0, q1 = up[1] + v1, q2 = up[2] + v2;
            float nrm = sqrtf(q0 * q0 + q1 * q1 + q2 * q2) + VN_EPS;
            s1 += nrm;
            s2 += nrm * nrm;
        }
    }
    __shared__ float r1[256], r2[256];
    r1[t] = s1; r2[t] = s2;
    __syncthreads();
    if (t < 64) {
        float a1 = r1[t] + r1[t + 64] + r1[t + 128] + r1[t + 192];
        float a2 = r2[t] + r2[t + 64] + r2[t + 128] + r2[t + 192];
        partial[(size_t)blk * 128 + t] = a1;
        partial[(size_t)blk * 128 + 64 + t] = a2;
    }
}

// ---------------- Kernel 6: reduce stats -> gs, bs ----------------
__global__ __launch_bounds__(256) void k_reduce(const float* __restrict__ partial,
                                                const float* __restrict__ gamma,
                                                const float* __restrict__ beta,
                                                float* __restrict__ gsbs) {
    int ch = blockIdx.x, t = threadIdx.x;
    float s1 = 0.f, s2 = 0.f;
    for (int i = t; i < 2048; i += 256) {
        s1 += partial[(size_t)i * 128 + ch];
        s2 += partial[(size_t)i * 128 + 64 + ch];
    }
    __shared__ float r1[256], r2[256];
    r1[t] = s1; r2[t] = s2;
    __syncthreads();
    for (int s = 128; s > 0; s >>= 1) {
        if (t < s) { r1[t] += r1[t + s]; r2[t] += r2[t + s]; }
        __syncthreads();
    }
    if (t == 0) {
        const float cnt = (float)(NB * NPTS * KNN);
        float mean = r1[0] / cnt;
        float var = r2[0] / cnt - mean * mean;
        float inv = 1.0f / sqrtf(var + VN_BN_EPS);
        float g = gamma[ch] * inv;
        gsbs[ch] = g;
        gsbs[64 + ch] = beta[ch] - mean * g;
    }
}

// ---------------- Kernel 7: fused BN + VN-LeakyReLU + mean, MFMA matvec ----------------
__global__ __launch_bounds__(256) void k_final(const float* __restrict__ u,
                                               const float* __restrict__ v,
                                               const int* __restrict__ idx,
                                               const float* __restrict__ Wd,
                                               const float* __restrict__ gsbs,
                                               float* __restrict__ out) {
    int t = threadIdx.x;
    int lane = t & 63, w = t >> 6;
    int l31 = lane & 31, hi = lane >> 5;
    int gpt = blockIdx.x * 4 + w;                 // global point b*N+n
    int b = gpt >> 13, n = gpt & 8191;

    __shared__ __align__(16) unsigned short Qls[4][30 * 72];  // f16
    __shared__ __align__(16) float Dls[4][30 * 64];           // f32
    unsigned short* Qw = Qls[w];
    float* Dw = Dls[w];

    f16x8 Bf[2][4];
    #pragma unroll
    for (int ct = 0; ct < 2; ++ct)
        #pragma unroll
        for (int ks = 0; ks < 4; ++ks) {
            const float* wp = Wd + (size_t)(ct * 32 + l31) * 64 + ks * 16 + hi * 8;
            f16x8 f;
            #pragma unroll
            for (int jj = 0; jj < 8; ++jj) f[jj] = (_Float16)wp[jj];
            Bf[ct][ks] = f;
        }

    float gso = gsbs[lane], bso = gsbs[64 + lane];
    size_t vb = (size_t)gpt * 192 + lane * 3;
    float v0 = v[vb], v1 = v[vb + 1], v2 = v[vb + 2];
    const int* jrow = idx + (size_t)gpt * KNN;
    size_t ubase = (size_t)b * NPTS * 192;
    float a0 = 0.f, a1 = 0.f, a2 = 0.f;

    for (int h = 0; h < 2; ++h) {
        #pragma unroll
        for (int kl = 0; kl < 10; ++kl) {
            int j = jrow[h * 10 + kl];
            const float* up = u + ubase + (size_t)j * 192 + lane * 3;
            float q0 = up[0] + v0, q1 = up[1] + v1, q2 = up[2] + v2;
            float nrm = sqrtf(q0 * q0 + q1 * q1 + q2 * q2) + VN_EPS;
            float f = (gso * nrm + bso) / nrm;
            q0 *= f; q1 *= f; q2 *= f;
            union { _Float16 f16; unsigned short u16; } c0, c1, c2;
            c0.f16 = (_Float16)q0; c1.f16 = (_Float16)q1; c2.f16 = (_Float16)q2;
            Qw[(3 * kl + 0) * 72 + lane] = c0.u16;
            Qw[(3 * kl + 1) * 72 + lane] = c1.u16;
            Qw[(3 * kl + 2) * 72 + lane] = c2.u16;
        }
        WAVESYNC();
        f32x16 acc[2];
        #pragma unroll
        for (int ct = 0; ct < 2; ++ct)
            #pragma unroll
            for (int e = 0; e < 16; ++e) acc[ct][e] = 0.f;
        #pragma unroll
        for (int ks = 0; ks < 4; ++ks) {
            f16x8 af = *(const f16x8*)&Qw[l31 * 72 + ks * 16 + hi * 8];
            acc[0] = __builtin_amdgcn_mfma_f32_32x32x16_f16(af, Bf[0][ks], acc[0], 0, 0, 0);
            acc[1] = __builtin_amdgcn_mfma_f32_32x32x16_f16(af, Bf[1][ks], acc[1], 0, 0, 0);
        }
        #pragma unroll
        for (int ct = 0; ct < 2; ++ct)
            #pragma unroll
            for (int q = 0; q < 4; ++q)
                #pragma unroll
                for (int r = 0; r < 4; ++r) {
                    int row = 4 * hi + 8 * q + r;
                    if (row < 30) Dw[row * 64 + ct * 32 + l31] = acc[ct][q * 4 + r];
                }
        WAVESYNC();
        #pragma unroll
        for (int kl = 0; kl < 10; ++kl) {
            float qd[3], dd[3];
            #pragma unroll
            for (int d = 0; d < 3; ++d) {
                union { unsigned short u16; _Float16 f16; } rr;
                rr.u16 = Qw[(3 * kl + d) * 72 + lane];
                qd[d] = (float)rr.f16;
                dd[d] = Dw[(3 * kl + d) * 64 + lane];
            }
            float dot = qd[0] * dd[0] + qd[1] * dd[1] + qd[2] * dd[2];
            float dn = dd[0] * dd[0] + dd[1] * dd[1] + dd[2] * dd[2];
            float coef = (dot >= 0.f) ? 0.f : 0.8f * dot / (dn + VN_EPS);
            a0 += qd[0] - coef * dd[0];
            a1 += qd[1] - coef * dd[1];
            a2 += qd[2] - coef * dd[2];
        }
        WAVESYNC();
    }
    float s = 1.f / (float)KNN;
    size_t ob = ((size_t)(b * 64 + lane) * 3) * NPTS + n;
    out[ob] = a0 * s;
    out[ob + NPTS] = a1 * s;
    out[ob + 2 * NPTS] = a2 * s;
}

// ---------------- host ----------------
extern "C" void kernel_launch(void* const* d_in, const int* in_sizes, int n_in,
                              void* d_out, int out_size, void* d_ws, size_t ws_size,
                              hipStream_t stream) {
    const float* x = (const float*)d_in[0];
    const float* W1 = (const float*)d_in[1];
    const float* Wd = (const float*)d_in[2];
    const float* gamma = (const float*)d_in[3];
    const float* beta = (const float*)d_in[4];
    float* out = (float*)d_out;

    char* ws = (char*)d_ws;
    size_t off = 0;
    auto alloc = [&](size_t bytes) {
        void* p = ws + off;
        off = (off + bytes + 255) & ~(size_t)255;
        return p;
    };
    float* xxp = (float*)alloc((size_t)NB * NPTS * 4);
    int* idxp = (int*)alloc((size_t)NB * NPTS * KNN * 4);
    float* up = (float*)alloc((size_t)NB * NPTS * 192 * 4);
    float* vp = (float*)alloc((size_t)NB * NPTS * 192 * 4);
    float* partial = (float*)alloc((size_t)2048 * 128 * 4);
    float* gsbs = (float*)alloc(512);
    unsigned short* xsp = (unsigned short*)alloc((size_t)NB * NPTS * 192 * 2);
    float* dbuf = (float*)(ws + off);

    const int totalRows = NB * NPTS;                 // 16384
    long avail = (long)ws_size - (long)off;
    long cap_l = avail / ((long)NPTS * 4);
    int cap = (int)((cap_l / 256) * 256);
    if (cap < 256) cap = 256;
    if (cap > 4096) cap = 4096;                      // 128 MB chunk, L3-resident

    k_prep<<<totalRows / 256, 256, 0, stream>>>(x, xxp, xsp);

    for (int start = 0; start < totalRows; start += cap) {
        int rows = totalRows - start;
        if (rows > cap) rows = cap;
        dim3 gg(rows / 256, NPTS / 256);
        k_dist<<<gg, 512, 0, stream>>>(xsp, xxp, dbuf, start);
        k_topk<<<rows, 256, 0, stream>>>(dbuf, idxp, start);
    }

    k_uv<<<totalRows / 16, 256, 0, stream>>>(x, W1, up, vp);
    k_stats<<<totalRows / 8, 256, 0, stream>>>(up, vp, idxp, partial);
    k_reduce<<<64, 256, 0, stream>>>(partial, gamma, beta, gsbs);
    k_final<<<totalRows / 4, 256, 0, stream>>>(up, vp, idxp, Wd, gsbs, out);
}